// Round 2
// baseline (1213.267 us; speedup 1.0000x reference)
//
#include <hip/hip_runtime.h>
#include <hip/hip_bf16.h>

typedef __attribute__((ext_vector_type(8))) short short8;
typedef __attribute__((ext_vector_type(4))) float floatx4;

__device__ __forceinline__ unsigned short f2bf(float x) {
    unsigned u = __float_as_uint(x);
    unsigned r = u + 0x7fffu + ((u >> 16) & 1u);   // RNE
    return (unsigned short)(r >> 16);
}

// ---------------- prep: f32 -> bf16 casts + Wrbf zero-pad to K=32 ----------------
__global__ void prep_kernel(const float* __restrict__ s,
                            const float* __restrict__ Ws1,
                            const float* __restrict__ Ws2,
                            const float* __restrict__ Wrbf,
                            unsigned short* __restrict__ s_bf,
                            unsigned short* __restrict__ ws1_bf,
                            unsigned short* __restrict__ ws2_bf,
                            unsigned short* __restrict__ wrbf_bf,
                            int n_s, int n_w1, int n_w2, int n_wrbf_out, int RB)
{
    int i = blockIdx.x * blockDim.x + threadIdx.x;
    int stride = gridDim.x * blockDim.x;
    int total = n_s + n_w1 + n_w2 + n_wrbf_out;
    for (; i < total; i += stride) {
        if (i < n_s) {
            s_bf[i] = f2bf(s[i]);
        } else if (i < n_s + n_w1) {
            int j = i - n_s;
            ws1_bf[j] = f2bf(Ws1[j]);
        } else if (i < n_s + n_w1 + n_w2) {
            int j = i - n_s - n_w1;
            ws2_bf[j] = f2bf(Ws2[j]);
        } else {
            int j = i - n_s - n_w1 - n_w2;
            int n = j >> 5, k = j & 31;
            wrbf_bf[j] = (k < RB) ? f2bf(Wrbf[n * RB + k]) : (unsigned short)0;
        }
    }
}

// ---------------- counting sort by dst: hist -> scan -> scatter ----------------
__global__ void hist_kernel(const int* __restrict__ eidx, int* __restrict__ cnt, int E) {
    int i = blockIdx.x * blockDim.x + threadIdx.x;
    if (i < E) atomicAdd(&cnt[eidx[i]], 1);   // eidx row0 = dst
}

__global__ void scan_kernel(const int* __restrict__ cnt, int* __restrict__ off, int Nn) {
    __shared__ int part[1024];
    int t = threadIdx.x;
    int C = (Nn + 1023) >> 10;
    int b = t * C, e = min(b + C, Nn);
    int s = 0;
    for (int i = b; i < e; ++i) s += cnt[i];
    part[t] = s;
    __syncthreads();
    for (int d = 1; d < 1024; d <<= 1) {
        int v = (t >= d) ? part[t - d] : 0;
        __syncthreads();
        part[t] += v;
        __syncthreads();
    }
    int excl = part[t] - s;
    for (int i = b; i < e; ++i) { off[i] = excl; excl += cnt[i]; }
    if (t == 1023) off[Nn] = part[1023];
}

__global__ void scatter_kernel(const int* __restrict__ eidx, const int* __restrict__ off,
                               int* __restrict__ fill, int* __restrict__ sorted, int E) {
    int i = blockIdx.x * blockDim.x + threadIdx.x;
    if (i < E) {
        int d = eidx[i];
        int p = off[d] + atomicAdd(&fill[d], 1);
        sorted[p] = i;
    }
}

// ---------------- main fused edge kernel, dst-ownership version ----------------
// One workgroup owns NPG consecutive dst nodes; processes their CSR edge range in
// chunks of 64 edges (4 waves x 16). Accumulation in LDS (ds_add_f32), one plain
// global write per owned node at the end. No global atomics.
#define LN   136   // padded row stride in shorts for S,H tiles
#define RLN  40    // padded row stride in shorts for rbf tile
#define NPG  8     // owned dst nodes per workgroup
#define ACCW 520   // padded float stride of per-node accumulator (512 data)

__global__ __launch_bounds__(256, 2)
void edge_kernel(const unsigned short* __restrict__ s_bf,
                 const float* __restrict__ vec,          // [Nn,3,128]
                 const float* __restrict__ edge_vec,     // [E,3]
                 const float* __restrict__ edge_dist,    // [E]
                 const float* __restrict__ edge_rbf,     // [E,RB]
                 const unsigned short* __restrict__ ws1_bf, // [128,128]
                 const float* __restrict__ bs1,          // [128]
                 const unsigned short* __restrict__ ws2_bf, // [384,128]
                 const float* __restrict__ bs2,          // [384]
                 const unsigned short* __restrict__ wrbf_bf, // [384,32]
                 const float* __restrict__ brbf,         // [384]
                 const int* __restrict__ eidx,           // [2,E]: row0=dst, row1=src
                 const void* __restrict__ cutoff_raw,
                 const int* __restrict__ node_off,       // [Nn+1] CSR offsets
                 const int* __restrict__ sorted_eid,     // [E] edge ids sorted by dst
                 float* __restrict__ out_ds,             // [Nn,128]
                 float* __restrict__ out_dvec,           // [Nn,3,128]
                 int E, int RB, int Nn)
{
    const int tid  = threadIdx.x;
    const int w    = tid >> 6;
    const int lane = tid & 63;
    const int l15  = lane & 15;
    const int q    = lane >> 4;
    const int node0 = blockIdx.x * NPG;

    // robust cutoff scalar decode (int32 / f32 / int64 / f64)
    float rc;
    {
        float fv = ((const float*)cutoff_raw)[0];
        int   iv = ((const int*)cutoff_raw)[0];
        if (fv > 0.099f && fv < 1.0e6f) rc = fv;
        else if (iv > 0 && iv < 1000000) rc = (float)iv;
        else {
            double dv = ((const double*)cutoff_raw)[0];
            if (dv > 0.099 && dv < 1.0e6) rc = (float)dv;
            else rc = (float)(((const long long*)cutoff_raw)[0]);
        }
    }

    __shared__ unsigned short S_bf[4][16][LN];
    __shared__ unsigned short H_bf[4][16][LN];
    __shared__ unsigned short R_bf[4][16][RLN];
    __shared__ int   m_src[4][16];
    __shared__ int   m_loc[4][16];     // dst - node0, in [0,NPG)
    __shared__ float m_fc [4][16];
    __shared__ float m_vn [4][16][3];
    __shared__ float acc[NPG * ACCW];  // [node][0:128]=ds, [128:512]=dvec(3x128)

    // zero the accumulators
    for (int i = tid; i < NPG * ACCW; i += 256) acc[i] = 0.0f;

    const int estart = node_off[node0];
    const int eend   = node_off[min(node0 + NPG, Nn)];
    const int nch    = (eend - estart + 63) >> 6;   // uniform across all 4 waves

    // hoist biases into registers (per-lane, indexed by l15)
    float b1R[8], b2R[3][8], brfR[3][8];
    #pragma unroll
    for (int j = 0; j < 8; ++j) b1R[j] = bs1[j * 16 + l15];
    #pragma unroll
    for (int g = 0; g < 3; ++g)
        #pragma unroll
        for (int j = 0; j < 8; ++j) {
            int n = g * 128 + j * 16 + l15;
            b2R[g][j]  = bs2[n];
            brfR[g][j] = brbf[n];
        }

    __syncthreads();   // acc zeroing visible to all waves

    for (int it = 0; it < nch; ++it) {
        const int base = estart + it * 64 + w * 16;

        // ---- per-edge meta (lanes 0..15 of each wave) ----
        if (lane < 16) {
            int p = base + lane;
            int valid = (p < eend);
            int e = valid ? sorted_eid[p] : 0;
            int isrc = 0, loc = 0;
            float fc = 0.0f, v0 = 0.0f, v1 = 0.0f, v2 = 0.0f;
            if (valid) {
                isrc = eidx[E + e];
                loc  = eidx[e] - node0;
                float d = edge_dist[e];
                if (d < rc) fc = 0.5f * (cosf(3.14159265358979323846f * d / rc) + 1.0f);
                float inv = 1.0f / d;
                v0 = edge_vec[e * 3 + 0] * inv;
                v1 = edge_vec[e * 3 + 1] * inv;
                v2 = edge_vec[e * 3 + 2] * inv;
            }
            m_src[w][lane] = isrc;
            m_loc[w][lane] = loc;
            m_fc [w][lane] = fc;
            m_vn [w][lane][0] = v0;
            m_vn [w][lane][1] = v1;
            m_vn [w][lane][2] = v2;
        }

        // ---- stage rbf tile [16][32] as bf16 (reads sorted_eid directly) ----
        for (int idx = lane; idx < 512; idx += 64) {
            int r = idx >> 5, c = idx & 31;
            int p = base + r;
            float v = 0.0f;
            if (p < eend && c < RB) {
                int e = sorted_eid[p];
                v = edge_rbf[e * RB + c];
            }
            R_bf[w][r][c] = f2bf(v);
        }
        __syncthreads();

        // ---- gather-stage S rows (bf16) ----
        #pragma unroll
        for (int itr = 0; itr < 4; ++itr) {
            int r = itr * 4 + q;
            int src = m_src[w][r];
            short8 v = ((const short8*)(s_bf + (size_t)src * 128))[l15];
            *((short8*)&S_bf[w][r][l15 * 8]) = v;
        }
        __syncthreads();

        // ---- GEMM1: h = silu(S @ Ws1^T + bs1) ----
        floatx4 acc1[8];
        #pragma unroll
        for (int nj = 0; nj < 8; ++nj) acc1[nj] = (floatx4){0.f, 0.f, 0.f, 0.f};
        #pragma unroll
        for (int ks = 0; ks < 4; ++ks) {
            short8 a = *((const short8*)&S_bf[w][l15][ks * 32 + q * 8]);
            #pragma unroll
            for (int nj = 0; nj < 8; ++nj) {
                short8 b = *((const short8*)(ws1_bf + ((nj * 16 + l15) * 128 + ks * 32 + q * 8)));
                acc1[nj] = __builtin_amdgcn_mfma_f32_16x16x32_bf16(a, b, acc1[nj], 0, 0, 0);
            }
        }
        #pragma unroll
        for (int nj = 0; nj < 8; ++nj) {
            #pragma unroll
            for (int r = 0; r < 4; ++r) {
                float x = acc1[nj][r] + b1R[nj];
                float h = x / (1.0f + __expf(-x));
                H_bf[w][q * 4 + r][nj * 16 + l15] = f2bf(h);
            }
        }
        __syncthreads();

        // ---- per-lane edge meta registers ----
        int locR[4], srcR[4];
        float fcR[4], vnR[4][3];
        #pragma unroll
        for (int r = 0; r < 4; ++r) {
            int row = q * 4 + r;
            locR[r] = m_loc[w][row];
            srcR[r] = m_src[w][row];
            fcR[r]  = m_fc [w][row];
            vnR[r][0] = m_vn[w][row][0];
            vnR[r][1] = m_vn[w][row][1];
            vnR[r][2] = m_vn[w][row][2];
        }
        bool sameDst = (locR[0] == locR[1]) && (locR[1] == locR[2]) && (locR[2] == locR[3]);

        // ---- GEMM2 + rbf MFMA + epilogue, 3 groups of N=128 ----
        float mvv[8][4];
        #pragma unroll
        for (int g = 0; g < 3; ++g) {
            floatx4 accP[8], accW[8];
            #pragma unroll
            for (int j = 0; j < 8; ++j) {
                accP[j] = (floatx4){0.f, 0.f, 0.f, 0.f};
                accW[j] = (floatx4){0.f, 0.f, 0.f, 0.f};
            }
            #pragma unroll
            for (int ks = 0; ks < 4; ++ks) {
                short8 a = *((const short8*)&H_bf[w][l15][ks * 32 + q * 8]);
                #pragma unroll
                for (int j = 0; j < 8; ++j) {
                    int n = g * 128 + j * 16 + l15;
                    short8 b = *((const short8*)(ws2_bf + ((size_t)n * 128 + ks * 32 + q * 8)));
                    accP[j] = __builtin_amdgcn_mfma_f32_16x16x32_bf16(a, b, accP[j], 0, 0, 0);
                }
            }
            {
                short8 ar = *((const short8*)&R_bf[w][l15][q * 8]);
                #pragma unroll
                for (int j = 0; j < 8; ++j) {
                    int n = g * 128 + j * 16 + l15;
                    short8 br = *((const short8*)(wrbf_bf + ((size_t)n * 32 + q * 8)));
                    accW[j] = __builtin_amdgcn_mfma_f32_16x16x32_bf16(ar, br, accW[j], 0, 0, 0);
                }
            }
            #pragma unroll
            for (int j = 0; j < 8; ++j) {
                int nl = j * 16 + l15;
                float msgs[4];
                #pragma unroll
                for (int r = 0; r < 4; ++r) {
                    float phi = accP[j][r] + b2R[g][j];
                    float Wv  = (accW[j][r] + brfR[g][j]) * fcR[r];
                    msgs[r] = phi * Wv;
                }
                if (g == 0) {
                    if (sameDst) {
                        atomicAdd(&acc[locR[0] * ACCW + nl],
                                  (msgs[0] + msgs[1]) + (msgs[2] + msgs[3]));
                    } else {
                        #pragma unroll
                        for (int r = 0; r < 4; ++r)
                            atomicAdd(&acc[locR[r] * ACCW + nl], msgs[r]);
                    }
                } else if (g == 1) {
                    #pragma unroll
                    for (int r = 0; r < 4; ++r) mvv[j][r] = msgs[r];
                } else {
                    #pragma unroll
                    for (int d = 0; d < 3; ++d) {
                        float c0, c1, c2, c3;
                        c0 = mvv[j][0] * vec[(size_t)srcR[0] * 384 + d * 128 + nl] + vnR[0][d] * msgs[0];
                        c1 = mvv[j][1] * vec[(size_t)srcR[1] * 384 + d * 128 + nl] + vnR[1][d] * msgs[1];
                        c2 = mvv[j][2] * vec[(size_t)srcR[2] * 384 + d * 128 + nl] + vnR[2][d] * msgs[2];
                        c3 = mvv[j][3] * vec[(size_t)srcR[3] * 384 + d * 128 + nl] + vnR[3][d] * msgs[3];
                        if (sameDst) {
                            atomicAdd(&acc[locR[0] * ACCW + 128 + d * 128 + nl],
                                      (c0 + c1) + (c2 + c3));
                        } else {
                            atomicAdd(&acc[locR[0] * ACCW + 128 + d * 128 + nl], c0);
                            atomicAdd(&acc[locR[1] * ACCW + 128 + d * 128 + nl], c1);
                            atomicAdd(&acc[locR[2] * ACCW + 128 + d * 128 + nl], c2);
                            atomicAdd(&acc[locR[3] * ACCW + 128 + d * 128 + nl], c3);
                        }
                    }
                }
            }
        }
        __syncthreads();   // tiles reused next chunk; keep waves phase-aligned
    }

    // ---- write owned nodes: plain coalesced float4 stores ----
    __syncthreads();
    for (int idx = tid; idx < NPG * 128; idx += 256) {   // 128 float4 per node
        int node = idx >> 7;
        int c4   = idx & 127;
        int gnode = node0 + node;
        if (gnode < Nn) {
            float4 v = *((const float4*)&acc[node * ACCW + c4 * 4]);
            if (c4 < 32) {
                *((float4*)&out_ds[(size_t)gnode * 128 + c4 * 4]) = v;
            } else {
                *((float4*)&out_dvec[(size_t)gnode * 384 + (c4 - 32) * 4]) = v;
            }
        }
    }
}

extern "C" void kernel_launch(void* const* d_in, const int* in_sizes, int n_in,
                              void* d_out, int out_size, void* d_ws, size_t ws_size,
                              hipStream_t stream) {
    const float* s        = (const float*)d_in[0];
    const float* vec      = (const float*)d_in[1];
    const float* edge_vec = (const float*)d_in[2];
    const float* edge_dst = (const float*)d_in[3];
    const float* edge_rbf = (const float*)d_in[4];
    const float* Ws1      = (const float*)d_in[5];
    const float* bs1      = (const float*)d_in[6];
    const float* Ws2      = (const float*)d_in[7];
    const float* bs2      = (const float*)d_in[8];
    const float* Wrbf     = (const float*)d_in[9];
    const float* brbf     = (const float*)d_in[10];
    const int*   eidx     = (const int*)d_in[11];
    const void*  cutoff   = d_in[12];

    const int F  = 128;
    const int Nn = in_sizes[0] / F;          // 10000
    const int E  = in_sizes[3];              // 200000
    const int RB = in_sizes[4] / E;          // 20
    const int F3 = 3 * F;                    // 384

    // ---- workspace layout ----
    unsigned short* s_bf    = (unsigned short*)d_ws;                  // Nn*128
    unsigned short* ws1_bf  = s_bf + (size_t)Nn * F;                  // 128*128
    unsigned short* ws2_bf  = ws1_bf + F * F;                         // 384*128
    unsigned short* wrbf_bf = ws2_bf + F3 * F;                        // 384*32
    int* cnt      = (int*)(wrbf_bf + F3 * 32);                        // Nn
    int* fill     = cnt + Nn;                                         // Nn
    int* node_off = fill + Nn;                                        // Nn+1
    int* sorted   = node_off + Nn + 1;                                // E

    int n_s = Nn * F, n_w1 = F * F, n_w2 = F3 * F, n_wr = F3 * 32;

    // zero hist + fill counters (re-poisoned to 0xAA before every launch)
    hipMemsetAsync(cnt, 0, (size_t)(2 * Nn) * sizeof(int), stream);

    {
        int total = n_s + n_w1 + n_w2 + n_wr;
        int blocks = (total + 255) / 256;
        prep_kernel<<<blocks, 256, 0, stream>>>(s, Ws1, Ws2, Wrbf,
                                                s_bf, ws1_bf, ws2_bf, wrbf_bf,
                                                n_s, n_w1, n_w2, n_wr, RB);
    }
    hist_kernel<<<(E + 255) / 256, 256, 0, stream>>>(eidx, cnt, E);
    scan_kernel<<<1, 1024, 0, stream>>>(cnt, node_off, Nn);
    scatter_kernel<<<(E + 255) / 256, 256, 0, stream>>>(eidx, node_off, fill, sorted, E);

    float* out_ds   = (float*)d_out;
    float* out_dvec = out_ds + (size_t)Nn * F;

    int blocks = (Nn + NPG - 1) / NPG;
    edge_kernel<<<blocks, 256, 0, stream>>>(s_bf, vec, edge_vec, edge_dst, edge_rbf,
                                            ws1_bf, bs1, ws2_bf, bs2, wrbf_bf, brbf,
                                            eidx, cutoff, node_off, sorted,
                                            out_ds, out_dvec, E, RB, Nn);
}

// Round 3
// 660.084 us; speedup vs baseline: 1.8380x; 1.8380x over previous
//
#include <hip/hip_runtime.h>
#include <hip/hip_bf16.h>

typedef __attribute__((ext_vector_type(8))) short short8;
typedef __attribute__((ext_vector_type(4))) float floatx4;

__device__ __forceinline__ unsigned short f2bf(float x) {
    unsigned u = __float_as_uint(x);
    unsigned r = u + 0x7fffu + ((u >> 16) & 1u);   // RNE
    return (unsigned short)(r >> 16);
}
__device__ __forceinline__ float bf2f(unsigned short h) {
    return __uint_as_float(((unsigned)h) << 16);
}

// ---------------- prep: weight f32 -> bf16 casts + Wrbf zero-pad to K=32 ----------------
__global__ void prep_kernel(const float* __restrict__ Ws1,
                            const float* __restrict__ Ws2,
                            const float* __restrict__ Wrbf,
                            unsigned short* __restrict__ ws1_bf,
                            unsigned short* __restrict__ ws2_bf,
                            unsigned short* __restrict__ wrbf_bf,
                            int n_w1, int n_w2, int n_wrbf_out, int RB)
{
    int i = blockIdx.x * blockDim.x + threadIdx.x;
    int stride = gridDim.x * blockDim.x;
    int total = n_w1 + n_w2 + n_wrbf_out;
    for (; i < total; i += stride) {
        if (i < n_w1) {
            ws1_bf[i] = f2bf(Ws1[i]);
        } else if (i < n_w1 + n_w2) {
            int j = i - n_w1;
            ws2_bf[j] = f2bf(Ws2[j]);
        } else {
            int j = i - n_w1 - n_w2;
            int n = j >> 5, k = j & 31;
            wrbf_bf[j] = (k < RB) ? f2bf(Wrbf[n * RB + k]) : (unsigned short)0;
        }
    }
}

// ---------------- node kernel: Phi = Linear2(silu(Linear1(s))) per NODE, bf16 out ----------
#define LN 136
__global__ __launch_bounds__(256, 2)
void node_kernel(const float* __restrict__ s,            // [Nn,128]
                 const unsigned short* __restrict__ ws1_bf, // [128,128]
                 const float* __restrict__ bs1,          // [128]
                 const unsigned short* __restrict__ ws2_bf, // [384,128]
                 const float* __restrict__ bs2,          // [384]
                 unsigned short* __restrict__ Phi_bf,    // [Nn,384]
                 int Nn)
{
    const int tid  = threadIdx.x;
    const int w    = tid >> 6;
    const int lane = tid & 63;
    const int l15  = lane & 15;
    const int q    = lane >> 4;
    const int base = blockIdx.x * 64 + w * 16;   // first node row of this wave

    __shared__ unsigned short S_bf[4][16][LN];
    __shared__ unsigned short H_bf[4][16][LN];

    // stage S rows (consecutive nodes, coalesced) with f32->bf16 conversion
    #pragma unroll
    for (int it = 0; it < 4; ++it) {
        int r = it * 4 + q;
        int node = base + r;
        short8 v;
        if (node < Nn) {
            const float* sp = s + (size_t)node * 128 + l15 * 8;
            #pragma unroll
            for (int k = 0; k < 8; ++k) v[k] = (short)f2bf(sp[k]);
        } else {
            #pragma unroll
            for (int k = 0; k < 8; ++k) v[k] = 0;
        }
        *((short8*)&S_bf[w][r][l15 * 8]) = v;
    }
    __syncthreads();

    // GEMM1: h = silu(S @ Ws1^T + bs1)
    floatx4 acc1[8];
    #pragma unroll
    for (int nj = 0; nj < 8; ++nj) acc1[nj] = (floatx4){0.f, 0.f, 0.f, 0.f};
    #pragma unroll
    for (int ks = 0; ks < 4; ++ks) {
        short8 a = *((const short8*)&S_bf[w][l15][ks * 32 + q * 8]);
        #pragma unroll
        for (int nj = 0; nj < 8; ++nj) {
            short8 b = *((const short8*)(ws1_bf + ((nj * 16 + l15) * 128 + ks * 32 + q * 8)));
            acc1[nj] = __builtin_amdgcn_mfma_f32_16x16x32_bf16(a, b, acc1[nj], 0, 0, 0);
        }
    }
    #pragma unroll
    for (int nj = 0; nj < 8; ++nj) {
        float b1 = bs1[nj * 16 + l15];
        #pragma unroll
        for (int r = 0; r < 4; ++r) {
            float x = acc1[nj][r] + b1;
            float h = x / (1.0f + __expf(-x));
            H_bf[w][q * 4 + r][nj * 16 + l15] = f2bf(h);
        }
    }
    __syncthreads();

    // GEMM2: phi = h @ Ws2^T + bs2, 3 groups of N=128, store bf16
    #pragma unroll
    for (int g = 0; g < 3; ++g) {
        floatx4 accP[8];
        #pragma unroll
        for (int j = 0; j < 8; ++j) accP[j] = (floatx4){0.f, 0.f, 0.f, 0.f};
        #pragma unroll
        for (int ks = 0; ks < 4; ++ks) {
            short8 a = *((const short8*)&H_bf[w][l15][ks * 32 + q * 8]);
            #pragma unroll
            for (int j = 0; j < 8; ++j) {
                int n = g * 128 + j * 16 + l15;
                short8 b = *((const short8*)(ws2_bf + ((size_t)n * 128 + ks * 32 + q * 8)));
                accP[j] = __builtin_amdgcn_mfma_f32_16x16x32_bf16(a, b, accP[j], 0, 0, 0);
            }
        }
        #pragma unroll
        for (int j = 0; j < 8; ++j) {
            int n = g * 128 + j * 16 + l15;
            float b2 = bs2[n];
            #pragma unroll
            for (int r = 0; r < 4; ++r) {
                int node = base + q * 4 + r;
                if (node < Nn)
                    Phi_bf[(size_t)node * 384 + n] = f2bf(accP[j][r] + b2);
            }
        }
    }
}

// ---------------- counting sort by dst: hist -> scan -> scatter(+meta) ----------------
__global__ void hist_kernel(const int* __restrict__ eidx, int* __restrict__ cnt, int E) {
    int i = blockIdx.x * blockDim.x + threadIdx.x;
    if (i < E) atomicAdd(&cnt[eidx[i]], 1);   // eidx row0 = dst
}

__global__ void scan_kernel(const int* __restrict__ cnt, int* __restrict__ off, int Nn) {
    __shared__ int part[1024];
    int t = threadIdx.x;
    int C = (Nn + 1023) >> 10;
    int b = t * C, e = min(b + C, Nn);
    int s = 0;
    for (int i = b; i < e; ++i) s += cnt[i];
    part[t] = s;
    __syncthreads();
    for (int d = 1; d < 1024; d <<= 1) {
        int v = (t >= d) ? part[t - d] : 0;
        __syncthreads();
        part[t] += v;
        __syncthreads();
    }
    int excl = part[t] - s;
    for (int i = b; i < e; ++i) { off[i] = excl; excl += cnt[i]; }
    if (t == 1023) off[Nn] = part[1023];
}

__global__ void scatter_kernel(const int* __restrict__ eidx,
                               const float* __restrict__ edge_vec,
                               const float* __restrict__ edge_dist,
                               const void* __restrict__ cutoff_raw,
                               const int* __restrict__ off,
                               int* __restrict__ fill,
                               int* __restrict__ sorted_eid,
                               int* __restrict__ sorted_src,
                               int* __restrict__ sorted_dst,
                               float4* __restrict__ sorted_meta,
                               int E)
{
    int i = blockIdx.x * blockDim.x + threadIdx.x;
    if (i >= E) return;
    // robust cutoff scalar decode (int32 / f32 / int64 / f64)
    float rc;
    {
        float fv = ((const float*)cutoff_raw)[0];
        int   iv = ((const int*)cutoff_raw)[0];
        if (fv > 0.099f && fv < 1.0e6f) rc = fv;
        else if (iv > 0 && iv < 1000000) rc = (float)iv;
        else {
            double dv = ((const double*)cutoff_raw)[0];
            if (dv > 0.099 && dv < 1.0e6) rc = (float)dv;
            else rc = (float)(((const long long*)cutoff_raw)[0]);
        }
    }
    int d = eidx[i];
    int p = off[d] + atomicAdd(&fill[d], 1);
    float dist = edge_dist[i];
    float fc = 0.0f;
    if (dist < rc) fc = 0.5f * (cosf(3.14159265358979323846f * dist / rc) + 1.0f);
    float inv = 1.0f / dist;
    sorted_eid[p] = i;
    sorted_src[p] = eidx[E + i];
    sorted_dst[p] = d;
    sorted_meta[p] = make_float4(edge_vec[i * 3 + 0] * inv,
                                 edge_vec[i * 3 + 1] * inv,
                                 edge_vec[i * 3 + 2] * inv, fc);
}

// ---------------- edge kernel: rbf MFMA + Phi/vec gather + LDS scatter-accumulate -------
#define RLN  48    // padded row stride in shorts for rbf tile (96B, 16B-aligned rows)
#define NPG  8     // owned dst nodes per workgroup
#define ACCW 520   // padded float stride of per-node accumulator (512 data)

__global__ __launch_bounds__(256, 4)
void edge_kernel(const unsigned short* __restrict__ Phi_bf, // [Nn,384]
                 const float* __restrict__ vec,             // [Nn,3,128]
                 const float* __restrict__ edge_rbf,        // [E,RB]
                 const unsigned short* __restrict__ wrbf_bf,// [384,32]
                 const float* __restrict__ brbf,            // [384]
                 const int* __restrict__ node_off,          // [Nn+1]
                 const int* __restrict__ sorted_eid,        // [E]
                 const int* __restrict__ sorted_src,        // [E]
                 const int* __restrict__ sorted_dst,        // [E]
                 const float4* __restrict__ sorted_meta,    // [E] (vn0,vn1,vn2,fc)
                 float* __restrict__ out_ds,                // [Nn,128]
                 float* __restrict__ out_dvec,              // [Nn,3,128]
                 int E, int RB, int Nn)
{
    const int tid  = threadIdx.x;
    const int w    = tid >> 6;
    const int lane = tid & 63;
    const int l15  = lane & 15;
    const int q    = lane >> 4;
    const int node0 = blockIdx.x * NPG;

    __shared__ unsigned short R_bf[4][16][RLN];
    __shared__ int   m_src[4][16];
    __shared__ int   m_loc[4][16];
    __shared__ float m_fc [4][16];
    __shared__ float m_vn [4][16][3];
    __shared__ float acc[NPG * ACCW];   // [node][0:128]=ds, [128:512]=dvec(3x128)

    for (int i = tid; i < NPG * ACCW; i += 256) acc[i] = 0.0f;

    const int estart = node_off[node0];
    const int eend   = node_off[min(node0 + NPG, Nn)];
    const int nch    = (eend - estart + 63) >> 6;

    __syncthreads();

    for (int it = 0; it < nch; ++it) {
        const int base = estart + it * 64 + w * 16;

        // ---- per-edge meta (lanes 0..15), all coalesced sorted-array reads ----
        if (lane < 16) {
            int p = base + lane;
            int src = 0, loc = 0;
            float4 f4 = make_float4(0.f, 0.f, 0.f, 0.f);
            if (p < eend) {
                src = sorted_src[p];
                loc = sorted_dst[p] - node0;
                f4  = sorted_meta[p];
            }
            m_src[w][lane] = src;
            m_loc[w][lane] = loc;
            m_fc [w][lane] = f4.w;
            m_vn [w][lane][0] = f4.x;
            m_vn [w][lane][1] = f4.y;
            m_vn [w][lane][2] = f4.z;
        }

        // ---- stage rbf tile [16][32] bf16 ----
        for (int idx = lane; idx < 512; idx += 64) {
            int r = idx >> 5, c = idx & 31;
            int p = base + r;
            float v = 0.0f;
            if (p < eend && c < RB) {
                int e = sorted_eid[p];
                v = edge_rbf[e * RB + c];
            }
            R_bf[w][r][c] = f2bf(v);
        }
        __syncthreads();

        int locR[4], srcR[4];
        float fcR[4], vnR[4][3];
        #pragma unroll
        for (int r = 0; r < 4; ++r) {
            int row = q * 4 + r;
            locR[r] = m_loc[w][row];
            srcR[r] = m_src[w][row];
            fcR[r]  = m_fc [w][row];
            vnR[r][0] = m_vn[w][row][0];
            vnR[r][1] = m_vn[w][row][1];
            vnR[r][2] = m_vn[w][row][2];
        }
        // sorted => loc monotone within chunk: endpoint equality implies all equal
        bool quadSame = (locR[0] == locR[3]);
        bool waveSame = (m_loc[w][0] == m_loc[w][15]);

        short8 ar = *((const short8*)&R_bf[w][l15][q * 8]);

        float mvv[8][4];
        #pragma unroll
        for (int g = 0; g < 3; ++g) {
            floatx4 accW[8];
            #pragma unroll
            for (int j = 0; j < 8; ++j) accW[j] = (floatx4){0.f, 0.f, 0.f, 0.f};
            #pragma unroll
            for (int j = 0; j < 8; ++j) {
                int n = g * 128 + j * 16 + l15;
                short8 br = *((const short8*)(wrbf_bf + ((size_t)n * 32 + q * 8)));
                accW[j] = __builtin_amdgcn_mfma_f32_16x16x32_bf16(ar, br, accW[j], 0, 0, 0);
            }
            #pragma unroll
            for (int j = 0; j < 8; ++j) {
                int nl = j * 16 + l15;
                int n  = g * 128 + nl;
                float brf = brbf[n];
                float msgs[4];
                #pragma unroll
                for (int r = 0; r < 4; ++r) {
                    float phi = bf2f(Phi_bf[(size_t)srcR[r] * 384 + n]);
                    float Wv  = (accW[j][r] + brf) * fcR[r];
                    msgs[r] = phi * Wv;
                }
                if (g == 0) {
                    if (waveSame) {
                        float tot = (msgs[0] + msgs[1]) + (msgs[2] + msgs[3]);
                        tot += __shfl_xor(tot, 16);
                        tot += __shfl_xor(tot, 32);
                        if (q == 0) atomicAdd(&acc[locR[0] * ACCW + nl], tot);
                    } else if (quadSame) {
                        atomicAdd(&acc[locR[0] * ACCW + nl],
                                  (msgs[0] + msgs[1]) + (msgs[2] + msgs[3]));
                    } else {
                        #pragma unroll
                        for (int r = 0; r < 4; ++r)
                            atomicAdd(&acc[locR[r] * ACCW + nl], msgs[r]);
                    }
                } else if (g == 1) {
                    #pragma unroll
                    for (int r = 0; r < 4; ++r) mvv[j][r] = msgs[r];
                } else {
                    #pragma unroll
                    for (int d = 0; d < 3; ++d) {
                        float c0 = mvv[j][0] * vec[(size_t)srcR[0] * 384 + d * 128 + nl] + vnR[0][d] * msgs[0];
                        float c1 = mvv[j][1] * vec[(size_t)srcR[1] * 384 + d * 128 + nl] + vnR[1][d] * msgs[1];
                        float c2 = mvv[j][2] * vec[(size_t)srcR[2] * 384 + d * 128 + nl] + vnR[2][d] * msgs[2];
                        float c3 = mvv[j][3] * vec[(size_t)srcR[3] * 384 + d * 128 + nl] + vnR[3][d] * msgs[3];
                        if (waveSame) {
                            float tot = (c0 + c1) + (c2 + c3);
                            tot += __shfl_xor(tot, 16);
                            tot += __shfl_xor(tot, 32);
                            if (q == 0) atomicAdd(&acc[locR[0] * ACCW + 128 + d * 128 + nl], tot);
                        } else if (quadSame) {
                            atomicAdd(&acc[locR[0] * ACCW + 128 + d * 128 + nl],
                                      (c0 + c1) + (c2 + c3));
                        } else {
                            atomicAdd(&acc[locR[0] * ACCW + 128 + d * 128 + nl], c0);
                            atomicAdd(&acc[locR[1] * ACCW + 128 + d * 128 + nl], c1);
                            atomicAdd(&acc[locR[2] * ACCW + 128 + d * 128 + nl], c2);
                            atomicAdd(&acc[locR[3] * ACCW + 128 + d * 128 + nl], c3);
                        }
                    }
                }
            }
        }
        __syncthreads();   // protect meta/R tiles + ensure atomics ordered per chunk
    }

    __syncthreads();
    // ---- write owned nodes: plain coalesced float4 stores ----
    for (int idx = tid; idx < NPG * 128; idx += 256) {
        int node = idx >> 7;
        int c4   = idx & 127;
        int gnode = node0 + node;
        if (gnode < Nn) {
            float4 v = *((const float4*)&acc[node * ACCW + c4 * 4]);
            if (c4 < 32) {
                *((float4*)&out_ds[(size_t)gnode * 128 + c4 * 4]) = v;
            } else {
                *((float4*)&out_dvec[(size_t)gnode * 384 + (c4 - 32) * 4]) = v;
            }
        }
    }
}

extern "C" void kernel_launch(void* const* d_in, const int* in_sizes, int n_in,
                              void* d_out, int out_size, void* d_ws, size_t ws_size,
                              hipStream_t stream) {
    const float* s        = (const float*)d_in[0];
    const float* vec      = (const float*)d_in[1];
    const float* edge_vec = (const float*)d_in[2];
    const float* edge_dst = (const float*)d_in[3];
    const float* edge_rbf = (const float*)d_in[4];
    const float* Ws1      = (const float*)d_in[5];
    const float* bs1      = (const float*)d_in[6];
    const float* Ws2      = (const float*)d_in[7];
    const float* bs2      = (const float*)d_in[8];
    const float* Wrbf     = (const float*)d_in[9];
    const float* brbf     = (const float*)d_in[10];
    const int*   eidx     = (const int*)d_in[11];
    const void*  cutoff   = d_in[12];

    const int F  = 128;
    const int Nn = in_sizes[0] / F;          // 10000
    const int E  = in_sizes[3];              // 200000
    const int RB = in_sizes[4] / E;          // 20
    const int F3 = 3 * F;                    // 384

    // ---- workspace layout (float4 first for alignment) ----
    float4* sorted_meta     = (float4*)d_ws;                          // E
    unsigned short* Phi_bf  = (unsigned short*)(sorted_meta + E);     // Nn*384
    unsigned short* ws1_bf  = Phi_bf + (size_t)Nn * F3;               // 128*128
    unsigned short* ws2_bf  = ws1_bf + F * F;                         // 384*128
    unsigned short* wrbf_bf = ws2_bf + F3 * F;                        // 384*32
    int* cnt        = (int*)(wrbf_bf + F3 * 32);                      // Nn
    int* fill       = cnt + Nn;                                       // Nn
    int* node_off   = fill + Nn;                                      // Nn+1
    int* sorted_eid = node_off + Nn + 1;                              // E
    int* sorted_src = sorted_eid + E;                                 // E
    int* sorted_dst = sorted_src + E;                                 // E

    int n_w1 = F * F, n_w2 = F3 * F, n_wr = F3 * 32;

    hipMemsetAsync(cnt, 0, (size_t)(2 * Nn) * sizeof(int), stream);

    {
        int total = n_w1 + n_w2 + n_wr;
        int blocks = (total + 255) / 256;
        prep_kernel<<<blocks, 256, 0, stream>>>(Ws1, Ws2, Wrbf,
                                                ws1_bf, ws2_bf, wrbf_bf,
                                                n_w1, n_w2, n_wr, RB);
    }
    node_kernel<<<(Nn + 63) / 64, 256, 0, stream>>>(s, ws1_bf, bs1, ws2_bf, bs2, Phi_bf, Nn);
    hist_kernel<<<(E + 255) / 256, 256, 0, stream>>>(eidx, cnt, E);
    scan_kernel<<<1, 1024, 0, stream>>>(cnt, node_off, Nn);
    scatter_kernel<<<(E + 255) / 256, 256, 0, stream>>>(eidx, edge_vec, edge_dst, cutoff,
                                                        node_off, fill, sorted_eid,
                                                        sorted_src, sorted_dst, sorted_meta, E);

    float* out_ds   = (float*)d_out;
    float* out_dvec = out_ds + (size_t)Nn * F;

    int blocks = (Nn + NPG - 1) / NPG;
    edge_kernel<<<blocks, 256, 0, stream>>>(Phi_bf, vec, edge_rbf, wrbf_bf, brbf,
                                            node_off, sorted_eid, sorted_src, sorted_dst,
                                            sorted_meta, out_ds, out_dvec, E, RB, Nn);
}

// Round 4
// 487.959 us; speedup vs baseline: 2.4864x; 1.3527x over previous
//
#include <hip/hip_runtime.h>
#include <hip/hip_bf16.h>

typedef __attribute__((ext_vector_type(8))) short short8;
typedef __attribute__((ext_vector_type(4))) float floatx4;

__device__ __forceinline__ unsigned short f2bf(float x) {
    unsigned u = __float_as_uint(x);
    unsigned r = u + 0x7fffu + ((u >> 16) & 1u);   // RNE
    return (unsigned short)(r >> 16);
}
__device__ __forceinline__ float bf2f(unsigned short h) {
    return __uint_as_float(((unsigned)h) << 16);
}

// ---------------- prep: bf16 casts (vec, weights) + Wrbf zero-pad to K=32 ----------------
__global__ void prep_kernel(const float* __restrict__ vec,
                            const float* __restrict__ Ws1,
                            const float* __restrict__ Ws2,
                            const float* __restrict__ Wrbf,
                            unsigned short* __restrict__ vecb,
                            unsigned short* __restrict__ ws1_bf,
                            unsigned short* __restrict__ ws2_bf,
                            unsigned short* __restrict__ wrbf_bf,
                            int n_vec, int n_w1, int n_w2, int n_wrbf_out, int RB)
{
    int i = blockIdx.x * blockDim.x + threadIdx.x;
    int stride = gridDim.x * blockDim.x;
    int total = n_vec + n_w1 + n_w2 + n_wrbf_out;
    for (; i < total; i += stride) {
        if (i < n_vec) {
            vecb[i] = f2bf(vec[i]);
        } else if (i < n_vec + n_w1) {
            int j = i - n_vec;
            ws1_bf[j] = f2bf(Ws1[j]);
        } else if (i < n_vec + n_w1 + n_w2) {
            int j = i - n_vec - n_w1;
            ws2_bf[j] = f2bf(Ws2[j]);
        } else {
            int j = i - n_vec - n_w1 - n_w2;
            int n = j >> 5, k = j & 31;
            wrbf_bf[j] = (k < RB) ? f2bf(Wrbf[n * RB + k]) : (unsigned short)0;
        }
    }
}

// ---------------- node kernel: Phi = Linear2(silu(Linear1(s))) per NODE, bf16 out ----------
#define LN 136
__global__ __launch_bounds__(256, 2)
void node_kernel(const float* __restrict__ s,            // [Nn,128]
                 const unsigned short* __restrict__ ws1_bf, // [128,128]
                 const float* __restrict__ bs1,          // [128]
                 const unsigned short* __restrict__ ws2_bf, // [384,128]
                 const float* __restrict__ bs2,          // [384]
                 unsigned short* __restrict__ Phi_bf,    // [Nn,384]
                 int Nn)
{
    const int tid  = threadIdx.x;
    const int w    = tid >> 6;
    const int lane = tid & 63;
    const int l15  = lane & 15;
    const int q    = lane >> 4;
    const int base = blockIdx.x * 64 + w * 16;

    __shared__ unsigned short S_bf[4][16][LN];
    __shared__ unsigned short H_bf[4][16][LN];

    #pragma unroll
    for (int it = 0; it < 4; ++it) {
        int r = it * 4 + q;
        int node = base + r;
        short8 v;
        if (node < Nn) {
            const float* sp = s + (size_t)node * 128 + l15 * 8;
            #pragma unroll
            for (int k = 0; k < 8; ++k) v[k] = (short)f2bf(sp[k]);
        } else {
            #pragma unroll
            for (int k = 0; k < 8; ++k) v[k] = 0;
        }
        *((short8*)&S_bf[w][r][l15 * 8]) = v;
    }
    __syncthreads();

    floatx4 acc1[8];
    #pragma unroll
    for (int nj = 0; nj < 8; ++nj) acc1[nj] = (floatx4){0.f, 0.f, 0.f, 0.f};
    #pragma unroll
    for (int ks = 0; ks < 4; ++ks) {
        short8 a = *((const short8*)&S_bf[w][l15][ks * 32 + q * 8]);
        #pragma unroll
        for (int nj = 0; nj < 8; ++nj) {
            short8 b = *((const short8*)(ws1_bf + ((nj * 16 + l15) * 128 + ks * 32 + q * 8)));
            acc1[nj] = __builtin_amdgcn_mfma_f32_16x16x32_bf16(a, b, acc1[nj], 0, 0, 0);
        }
    }
    #pragma unroll
    for (int nj = 0; nj < 8; ++nj) {
        float b1 = bs1[nj * 16 + l15];
        #pragma unroll
        for (int r = 0; r < 4; ++r) {
            float x = acc1[nj][r] + b1;
            float h = x / (1.0f + __expf(-x));
            H_bf[w][q * 4 + r][nj * 16 + l15] = f2bf(h);
        }
    }
    __syncthreads();

    #pragma unroll
    for (int g = 0; g < 3; ++g) {
        floatx4 accP[8];
        #pragma unroll
        for (int j = 0; j < 8; ++j) accP[j] = (floatx4){0.f, 0.f, 0.f, 0.f};
        #pragma unroll
        for (int ks = 0; ks < 4; ++ks) {
            short8 a = *((const short8*)&H_bf[w][l15][ks * 32 + q * 8]);
            #pragma unroll
            for (int j = 0; j < 8; ++j) {
                int n = g * 128 + j * 16 + l15;
                short8 b = *((const short8*)(ws2_bf + ((size_t)n * 128 + ks * 32 + q * 8)));
                accP[j] = __builtin_amdgcn_mfma_f32_16x16x32_bf16(a, b, accP[j], 0, 0, 0);
            }
        }
        #pragma unroll
        for (int j = 0; j < 8; ++j) {
            int n = g * 128 + j * 16 + l15;
            float b2 = bs2[n];
            #pragma unroll
            for (int r = 0; r < 4; ++r) {
                int node = base + q * 4 + r;
                if (node < Nn)
                    Phi_bf[(size_t)node * 384 + n] = f2bf(accP[j][r] + b2);
            }
        }
    }
}

// ---------------- counting sort by dst: hist -> scan -> scatter(+meta) ----------------
__global__ void hist_kernel(const int* __restrict__ eidx, int* __restrict__ cnt, int E) {
    int i = blockIdx.x * blockDim.x + threadIdx.x;
    if (i < E) atomicAdd(&cnt[eidx[i]], 1);   // eidx row0 = dst
}

__global__ void scan_kernel(const int* __restrict__ cnt, int* __restrict__ off, int Nn) {
    __shared__ int part[1024];
    int t = threadIdx.x;
    int C = (Nn + 1023) >> 10;
    int b = t * C, e = min(b + C, Nn);
    int s = 0;
    for (int i = b; i < e; ++i) s += cnt[i];
    part[t] = s;
    __syncthreads();
    for (int d = 1; d < 1024; d <<= 1) {
        int v = (t >= d) ? part[t - d] : 0;
        __syncthreads();
        part[t] += v;
        __syncthreads();
    }
    int excl = part[t] - s;
    for (int i = b; i < e; ++i) { off[i] = excl; excl += cnt[i]; }
    if (t == 1023) off[Nn] = part[1023];
}

__global__ void scatter_kernel(const int* __restrict__ eidx,
                               const float* __restrict__ edge_vec,
                               const float* __restrict__ edge_dist,
                               const void* __restrict__ cutoff_raw,
                               const int* __restrict__ off,
                               int* __restrict__ fill,
                               int* __restrict__ sorted_eid,
                               int* __restrict__ sorted_src,
                               int* __restrict__ sorted_dst,
                               float4* __restrict__ sorted_meta,
                               int E)
{
    int i = blockIdx.x * blockDim.x + threadIdx.x;
    if (i >= E) return;
    float rc;
    {
        float fv = ((const float*)cutoff_raw)[0];
        int   iv = ((const int*)cutoff_raw)[0];
        if (fv > 0.099f && fv < 1.0e6f) rc = fv;
        else if (iv > 0 && iv < 1000000) rc = (float)iv;
        else {
            double dv = ((const double*)cutoff_raw)[0];
            if (dv > 0.099 && dv < 1.0e6) rc = (float)dv;
            else rc = (float)(((const long long*)cutoff_raw)[0]);
        }
    }
    int d = eidx[i];
    int p = off[d] + atomicAdd(&fill[d], 1);
    float dist = edge_dist[i];
    float fc = 0.0f;
    if (dist < rc) fc = 0.5f * (cosf(3.14159265358979323846f * dist / rc) + 1.0f);
    float inv = 1.0f / dist;
    sorted_eid[p] = i;
    sorted_src[p] = eidx[E + i];
    sorted_dst[p] = d;
    sorted_meta[p] = make_float4(edge_vec[i * 3 + 0] * inv,
                                 edge_vec[i * 3 + 1] * inv,
                                 edge_vec[i * 3 + 2] * inv, fc);
}

// ---------------- edge kernel: barrier-free streaming, LDS accumulate ----------------
#define RLN  40    // padded row stride in shorts for rbf tile (80 B)
#define NPG  8     // owned dst nodes per workgroup
#define ACCW 520   // padded float stride of per-node accumulator (512 data)

__global__ __launch_bounds__(256, 2)
void edge_kernel(const unsigned short* __restrict__ Phi_bf, // [Nn,384]
                 const unsigned short* __restrict__ vecb,   // [Nn,3,128] bf16
                 const float* __restrict__ edge_rbf,        // [E,RB]
                 const unsigned short* __restrict__ wrbf_bf,// [384,32]
                 const float* __restrict__ brbf,            // [384]
                 const int* __restrict__ node_off,          // [Nn+1]
                 const int* __restrict__ sorted_eid,        // [E]
                 const int* __restrict__ sorted_src,        // [E]
                 const int* __restrict__ sorted_dst,        // [E]
                 const float4* __restrict__ sorted_meta,    // [E] (vn0,vn1,vn2,fc)
                 float* __restrict__ out_ds,                // [Nn,128]
                 float* __restrict__ out_dvec,              // [Nn,3,128]
                 int E, int RB, int Nn)
{
    const int tid  = threadIdx.x;
    const int w    = tid >> 6;
    const int lane = tid & 63;
    const int l15  = lane & 15;
    const int q    = lane >> 4;
    const int node0 = blockIdx.x * NPG;

    __shared__ unsigned short R_bf[4][16][RLN];
    __shared__ int   m_src[4][16];
    __shared__ int   m_loc[4][16];
    __shared__ float m_fc [4][16];
    __shared__ float m_vn [4][16][3];
    __shared__ float acc[NPG * ACCW];   // [node][0:128]=ds, [128:512]=dvec(3x128)

    for (int i = tid; i < NPG * ACCW; i += 256) acc[i] = 0.0f;

    const int estart = node_off[node0];
    const int eend   = node_off[min(node0 + NPG, Nn)];

    __syncthreads();   // acc zero visible before any atomics

    // Each wave streams its own 16-edge chunks; NO inter-wave barriers inside.
    for (int base = estart + w * 16; base < eend; base += 64) {

        // per-edge meta (lanes 0..15) — wave-internal LDS, no barrier needed
        if (lane < 16) {
            int p = base + lane;
            int src = 0, loc = 0;
            float4 f4 = make_float4(0.f, 0.f, 0.f, 0.f);
            if (p < eend) {
                src = sorted_src[p];
                loc = sorted_dst[p] - node0;
                f4  = sorted_meta[p];
            }
            m_src[w][lane] = src;
            m_loc[w][lane] = loc;
            m_fc [w][lane] = f4.w;
            m_vn [w][lane][0] = f4.x;
            m_vn [w][lane][1] = f4.y;
            m_vn [w][lane][2] = f4.z;
        }

        // rbf tile [16][32] bf16 (K zero-padded)
        for (int idx = lane; idx < 512; idx += 64) {
            int r = idx >> 5, c = idx & 31;
            int p = base + r;
            float v = 0.0f;
            if (p < eend && c < RB) {
                int e = sorted_eid[p];
                v = edge_rbf[e * RB + c];
            }
            R_bf[w][r][c] = f2bf(v);
        }

        int locR[4], srcR[4];
        float fcR[4], vnR[4][3];
        #pragma unroll
        for (int r = 0; r < 4; ++r) {
            int row = q * 4 + r;
            locR[r] = m_loc[w][row];
            srcR[r] = m_src[w][row];
            fcR[r]  = m_fc [w][row];
            vnR[r][0] = m_vn[w][row][0];
            vnR[r][1] = m_vn[w][row][1];
            vnR[r][2] = m_vn[w][row][2];
        }
        // sorted => loc monotone; invalid tail lanes contribute 0 so misattribution is safe
        bool quadSame = (locR[0] == locR[3]);
        bool waveSame = (m_loc[w][0] == m_loc[w][15]);

        short8 ar = *((const short8*)&R_bf[w][l15][q * 8]);

        float mvv[8][4];
        #pragma unroll
        for (int g = 0; g < 3; ++g) {
            floatx4 accW[8];
            #pragma unroll
            for (int j = 0; j < 8; ++j) accW[j] = (floatx4){0.f, 0.f, 0.f, 0.f};
            #pragma unroll
            for (int j = 0; j < 8; ++j) {
                int n = g * 128 + j * 16 + l15;
                short8 br = *((const short8*)(wrbf_bf + ((size_t)n * 32 + q * 8)));
                accW[j] = __builtin_amdgcn_mfma_f32_16x16x32_bf16(ar, br, accW[j], 0, 0, 0);
            }
            #pragma unroll
            for (int j = 0; j < 8; ++j) {
                int nl = j * 16 + l15;
                int n  = g * 128 + nl;
                float brf = brbf[n];
                float msgs[4];
                #pragma unroll
                for (int r = 0; r < 4; ++r) {
                    float phi = bf2f(Phi_bf[(size_t)srcR[r] * 384 + n]);
                    float Wv  = (accW[j][r] + brf) * fcR[r];
                    msgs[r] = phi * Wv;
                }
                if (g == 0) {
                    if (waveSame) {
                        float tot = (msgs[0] + msgs[1]) + (msgs[2] + msgs[3]);
                        tot += __shfl_xor(tot, 16);
                        tot += __shfl_xor(tot, 32);
                        if (q == 0) atomicAdd(&acc[locR[0] * ACCW + nl], tot);
                    } else if (quadSame) {
                        atomicAdd(&acc[locR[0] * ACCW + nl],
                                  (msgs[0] + msgs[1]) + (msgs[2] + msgs[3]));
                    } else {
                        #pragma unroll
                        for (int r = 0; r < 4; ++r)
                            atomicAdd(&acc[locR[r] * ACCW + nl], msgs[r]);
                    }
                } else if (g == 1) {
                    #pragma unroll
                    for (int r = 0; r < 4; ++r) mvv[j][r] = msgs[r];
                } else {
                    #pragma unroll
                    for (int d = 0; d < 3; ++d) {
                        float c0 = mvv[j][0] * bf2f(vecb[(size_t)srcR[0] * 384 + d * 128 + nl]) + vnR[0][d] * msgs[0];
                        float c1 = mvv[j][1] * bf2f(vecb[(size_t)srcR[1] * 384 + d * 128 + nl]) + vnR[1][d] * msgs[1];
                        float c2 = mvv[j][2] * bf2f(vecb[(size_t)srcR[2] * 384 + d * 128 + nl]) + vnR[2][d] * msgs[2];
                        float c3 = mvv[j][3] * bf2f(vecb[(size_t)srcR[3] * 384 + d * 128 + nl]) + vnR[3][d] * msgs[3];
                        if (waveSame) {
                            float tot = (c0 + c1) + (c2 + c3);
                            tot += __shfl_xor(tot, 16);
                            tot += __shfl_xor(tot, 32);
                            if (q == 0) atomicAdd(&acc[locR[0] * ACCW + 128 + d * 128 + nl], tot);
                        } else if (quadSame) {
                            atomicAdd(&acc[locR[0] * ACCW + 128 + d * 128 + nl],
                                      (c0 + c1) + (c2 + c3));
                        } else {
                            atomicAdd(&acc[locR[0] * ACCW + 128 + d * 128 + nl], c0);
                            atomicAdd(&acc[locR[1] * ACCW + 128 + d * 128 + nl], c1);
                            atomicAdd(&acc[locR[2] * ACCW + 128 + d * 128 + nl], c2);
                            atomicAdd(&acc[locR[3] * ACCW + 128 + d * 128 + nl], c3);
                        }
                    }
                }
            }
        }
    }

    __syncthreads();   // all waves done accumulating
    for (int idx = tid; idx < NPG * 128; idx += 256) {
        int node = idx >> 7;
        int c4   = idx & 127;
        int gnode = node0 + node;
        if (gnode < Nn) {
            float4 v = *((const float4*)&acc[node * ACCW + c4 * 4]);
            if (c4 < 32) {
                *((float4*)&out_ds[(size_t)gnode * 128 + c4 * 4]) = v;
            } else {
                *((float4*)&out_dvec[(size_t)gnode * 384 + (c4 - 32) * 4]) = v;
            }
        }
    }
}

extern "C" void kernel_launch(void* const* d_in, const int* in_sizes, int n_in,
                              void* d_out, int out_size, void* d_ws, size_t ws_size,
                              hipStream_t stream) {
    const float* s        = (const float*)d_in[0];
    const float* vec      = (const float*)d_in[1];
    const float* edge_vec = (const float*)d_in[2];
    const float* edge_dst = (const float*)d_in[3];
    const float* edge_rbf = (const float*)d_in[4];
    const float* Ws1      = (const float*)d_in[5];
    const float* bs1      = (const float*)d_in[6];
    const float* Ws2      = (const float*)d_in[7];
    const float* bs2      = (const float*)d_in[8];
    const float* Wrbf     = (const float*)d_in[9];
    const float* brbf     = (const float*)d_in[10];
    const int*   eidx     = (const int*)d_in[11];
    const void*  cutoff   = d_in[12];

    const int F  = 128;
    const int Nn = in_sizes[0] / F;          // 10000
    const int E  = in_sizes[3];              // 200000
    const int RB = in_sizes[4] / E;          // 20
    const int F3 = 3 * F;                    // 384

    // ---- workspace layout (float4 first for alignment) ----
    float4* sorted_meta     = (float4*)d_ws;                          // E
    unsigned short* Phi_bf  = (unsigned short*)(sorted_meta + E);     // Nn*384
    unsigned short* vecb    = Phi_bf + (size_t)Nn * F3;               // Nn*384
    unsigned short* ws1_bf  = vecb + (size_t)Nn * F3;                 // 128*128
    unsigned short* ws2_bf  = ws1_bf + F * F;                         // 384*128
    unsigned short* wrbf_bf = ws2_bf + F3 * F;                        // 384*32
    int* cnt        = (int*)(wrbf_bf + F3 * 32);                      // Nn
    int* fill       = cnt + Nn;                                       // Nn
    int* node_off   = fill + Nn;                                      // Nn+1
    int* sorted_eid = node_off + Nn + 1;                              // E
    int* sorted_src = sorted_eid + E;                                 // E
    int* sorted_dst = sorted_src + E;                                 // E

    int n_vec = Nn * F3, n_w1 = F * F, n_w2 = F3 * F, n_wr = F3 * 32;

    hipMemsetAsync(cnt, 0, (size_t)(2 * Nn) * sizeof(int), stream);

    {
        int total = n_vec + n_w1 + n_w2 + n_wr;
        int blocks = (total + 1023) / 1024;   // grid-stride, ~4 elems/thread
        prep_kernel<<<blocks, 256, 0, stream>>>(vec, Ws1, Ws2, Wrbf,
                                                vecb, ws1_bf, ws2_bf, wrbf_bf,
                                                n_vec, n_w1, n_w2, n_wr, RB);
    }
    node_kernel<<<(Nn + 63) / 64, 256, 0, stream>>>(s, ws1_bf, bs1, ws2_bf, bs2, Phi_bf, Nn);
    hist_kernel<<<(E + 255) / 256, 256, 0, stream>>>(eidx, cnt, E);
    scan_kernel<<<1, 1024, 0, stream>>>(cnt, node_off, Nn);
    scatter_kernel<<<(E + 255) / 256, 256, 0, stream>>>(eidx, edge_vec, edge_dst, cutoff,
                                                        node_off, fill, sorted_eid,
                                                        sorted_src, sorted_dst, sorted_meta, E);

    float* out_ds   = (float*)d_out;
    float* out_dvec = out_ds + (size_t)Nn * F;

    int blocks = (Nn + NPG - 1) / NPG;
    edge_kernel<<<blocks, 256, 0, stream>>>(Phi_bf, vecb, edge_rbf, wrbf_bf, brbf,
                                            node_off, sorted_eid, sorted_src, sorted_dst,
                                            sorted_meta, out_ds, out_dvec, E, RB, Nn);
}